// Round 2
// baseline (288.009 us; speedup 1.0000x reference)
//
#include <hip/hip_runtime.h>
#include <math.h>

#define BN 8192       // batch size (rows of sim)
#define DF 128        // feature dim
#define NSPLIT 16     // column splits per row-block
#define ROWS_PER_BLK 64
#define EPSV 1e-5f
#define THRESH 0.5f

typedef short bf16x8 __attribute__((ext_vector_type(8)));
typedef float f32x4 __attribute__((ext_vector_type(4)));
typedef unsigned short ushortx8 __attribute__((ext_vector_type(8)));

static __device__ __forceinline__ unsigned short f2bf(float f) {
    unsigned u = __float_as_uint(f);
    u += 0x7FFFu + ((u >> 16) & 1u);   // round-to-nearest-even
    return (unsigned short)(u >> 16);
}

// ---------------- kernel 0: f32 -> bf16 convert ----------------
__global__ __launch_bounds__(256) void convert_kernel(const float* __restrict__ in,
                                                      unsigned short* __restrict__ out) {
    int gid = blockIdx.x * 256 + threadIdx.x;       // 8 elems per thread
    const float4* inp = reinterpret_cast<const float4*>(in) + (size_t)gid * 2;
    float4 v0 = inp[0], v1 = inp[1];
    ushortx8 o;
    o[0] = f2bf(v0.x); o[1] = f2bf(v0.y); o[2] = f2bf(v0.z); o[3] = f2bf(v0.w);
    o[4] = f2bf(v1.x); o[5] = f2bf(v1.y); o[6] = f2bf(v1.z); o[7] = f2bf(v1.w);
    *reinterpret_cast<ushortx8*>(out + (size_t)gid * 8) = o;
}

// ---------------- kernel 1: per-row min_pos / max_neg ----------------
__global__ __launch_bounds__(256, 8) void phase1_kernel(const unsigned short* __restrict__ fb,
                                                        const int* __restrict__ labels,
                                                        float* __restrict__ minp_out,
                                                        float* __restrict__ maxn_out) {
    const int tid  = threadIdx.x;
    const int wave = tid >> 6, lane = tid & 63;
    const int rowblk = blockIdx.x >> 4;            // / NSPLIT
    const int split  = blockIdx.x & (NSPLIT - 1);
    const int m0w = rowblk * ROWS_PER_BLK + wave * 16;
    const int l4 = lane & 15, g = lane >> 4;

    // A fragments for this wave's 16 rows, all of K=128 (hoisted; rows fixed)
    bf16x8 afrag[4];
    const int arow = m0w + l4;
    #pragma unroll
    for (int kk = 0; kk < 4; ++kk)
        afrag[kk] = *reinterpret_cast<const bf16x8*>(fb + arow * DF + kk * 32 + g * 8);

    int rrow[4], labr[4];
    #pragma unroll
    for (int r = 0; r < 4; ++r) { rrow[r] = m0w + g * 4 + r; labr[r] = labels[rrow[r]]; }

    float minp[4], maxn[4];
    #pragma unroll
    for (int r = 0; r < 4; ++r) { minp[r] = INFINITY; maxn[r] = -INFINITY; }

    const int n_begin = split * (BN / NSPLIT);
    const int n_end   = n_begin + (BN / NSPLIT);
    for (int n0 = n_begin; n0 < n_end; n0 += 16) {
        const int col  = n0 + l4;
        const int labc = labels[col];
        const unsigned short* bp = fb + col * DF + g * 8;
        f32x4 acc = {0.f, 0.f, 0.f, 0.f};
        #pragma unroll
        for (int kk = 0; kk < 4; ++kk) {
            bf16x8 bfrag = *reinterpret_cast<const bf16x8*>(bp + kk * 32);
            acc = __builtin_amdgcn_mfma_f32_16x16x32_bf16(afrag[kk], bfrag, acc, 0, 0, 0);
        }
        #pragma unroll
        for (int r = 0; r < 4; ++r) {
            float s = acc[r];
            bool same = (labc == labr[r]);
            bool posc = same && (col != rrow[r]) && (s < 1.0f - EPSV);
            minp[r] = fminf(minp[r], posc ? s : INFINITY);
            maxn[r] = fmaxf(maxn[r], same ? -INFINITY : s);
        }
    }
    #pragma unroll
    for (int r = 0; r < 4; ++r) {
        #pragma unroll
        for (int m = 1; m < 16; m <<= 1) {
            minp[r] = fminf(minp[r], __shfl_xor(minp[r], m, 64));
            maxn[r] = fmaxf(maxn[r], __shfl_xor(maxn[r], m, 64));
        }
        if (l4 == 0) {
            minp_out[split * BN + rrow[r]] = minp[r];
            maxn_out[split * BN + rrow[r]] = maxn[r];
        }
    }
}

// ---------------- kernel 2: masked exp sums ----------------
__global__ __launch_bounds__(256, 8) void phase2_kernel(const unsigned short* __restrict__ fb,
                                                        const int* __restrict__ labels,
                                                        const float* __restrict__ minp_part,
                                                        const float* __restrict__ maxn_part,
                                                        float* __restrict__ pos_sum,
                                                        float* __restrict__ neg_sum,
                                                        const float* __restrict__ margin_p,
                                                        const float* __restrict__ sp_p,
                                                        const float* __restrict__ sn_p) {
    const int tid  = threadIdx.x;
    const int wave = tid >> 6, lane = tid & 63;
    const int rowblk = blockIdx.x >> 4;
    const int split  = blockIdx.x & (NSPLIT - 1);
    const int m0w = rowblk * ROWS_PER_BLK + wave * 16;
    const int l4 = lane & 15, g = lane >> 4;

    const float margin = *margin_p;
    const float sp = *sp_p, sn = *sn_p;
    const float L2E = 1.4426950408889634f;
    const float a_pos = -sp * L2E, b_pos =  sp * THRESH * L2E;
    const float a_neg =  sn * L2E, b_neg = -sn * THRESH * L2E;

    bf16x8 afrag[4];
    const int arow = m0w + l4;
    #pragma unroll
    for (int kk = 0; kk < 4; ++kk)
        afrag[kk] = *reinterpret_cast<const bf16x8*>(fb + arow * DF + kk * 32 + g * 8);

    int rrow[4], labr[4];
    float thrn[4], tpos[4];
    #pragma unroll
    for (int r = 0; r < 4; ++r) {
        rrow[r] = m0w + g * 4 + r;
        labr[r] = labels[rrow[r]];
        float mp = INFINITY, mn = -INFINITY;
        #pragma unroll
        for (int s = 0; s < NSPLIT; ++s) {
            mp = fminf(mp, minp_part[s * BN + rrow[r]]);
            mn = fmaxf(mn, maxn_part[s * BN + rrow[r]]);
        }
        thrn[r] = mp - margin;                         // neg pair needs sim > thrn
        tpos[r] = fminf(mn + margin, 1.0f - EPSV);     // pos pair needs sim < tpos
    }

    float psum[4] = {0.f, 0.f, 0.f, 0.f};
    float nsum[4] = {0.f, 0.f, 0.f, 0.f};

    const int n_begin = split * (BN / NSPLIT);
    const int n_end   = n_begin + (BN / NSPLIT);
    for (int n0 = n_begin; n0 < n_end; n0 += 16) {
        const int col  = n0 + l4;
        const int labc = labels[col];
        const unsigned short* bp = fb + col * DF + g * 8;
        f32x4 acc = {0.f, 0.f, 0.f, 0.f};
        #pragma unroll
        for (int kk = 0; kk < 4; ++kk) {
            bf16x8 bfrag = *reinterpret_cast<const bf16x8*>(bp + kk * 32);
            acc = __builtin_amdgcn_mfma_f32_16x16x32_bf16(afrag[kk], bfrag, acc, 0, 0, 0);
        }
        #pragma unroll
        for (int r = 0; r < 4; ++r) {
            float s = acc[r];
            bool same = (labc == labr[r]);
            bool posc = same && (col != rrow[r]) && (s < tpos[r]);
            bool negc = (!same) && (s > thrn[r]);
            // one exp for both cases: coefficients selected per-lane (log2 domain)
            float aa = same ? a_pos : a_neg;
            float bb = same ? b_pos : b_neg;
            float e  = __builtin_amdgcn_exp2f(fmaf(aa, s, bb));
            psum[r] += posc ? e : 0.f;
            nsum[r] += negc ? e : 0.f;
        }
    }
    #pragma unroll
    for (int r = 0; r < 4; ++r) {
        #pragma unroll
        for (int m = 1; m < 16; m <<= 1) {
            psum[r] += __shfl_xor(psum[r], m, 64);
            nsum[r] += __shfl_xor(nsum[r], m, 64);
        }
        if (l4 == 0) {
            atomicAdd(&pos_sum[rrow[r]], psum[r]);
            atomicAdd(&neg_sum[rrow[r]], nsum[r]);
        }
    }
}

// ---------------- kernel 3: finalize ----------------
__global__ __launch_bounds__(256) void finalize_kernel(const float* __restrict__ pos_sum,
                                                       const float* __restrict__ neg_sum,
                                                       const float* __restrict__ sp_p,
                                                       const float* __restrict__ sn_p,
                                                       float* __restrict__ out) {
    const int tid  = threadIdx.x;
    const int wave = tid >> 6, lane = tid & 63;
    const float sp = *sp_p, sn = *sn_p;
    float lsum = 0.f, ncnt = 0.f;
    for (int r = tid; r < BN; r += 256) {
        float ps = pos_sum[r], ns = neg_sum[r];
        bool hasp = ps > 0.f, hasn = ns > 0.f;
        if (hasp && hasn) lsum += log1pf(ps) / sp + log1pf(ns) / sn;
        if (!hasn) ncnt += 1.f;
    }
    #pragma unroll
    for (int m = 1; m < 64; m <<= 1) {
        lsum += __shfl_xor(lsum, m, 64);
        ncnt += __shfl_xor(ncnt, m, 64);
    }
    __shared__ float sdata[8];
    if (lane == 0) { sdata[wave] = lsum; sdata[4 + wave] = ncnt; }
    __syncthreads();
    if (tid == 0) {
        float t = 0.f, c = 0.f;
        for (int i = 0; i < 4; ++i) { t += sdata[i]; c += sdata[4 + i]; }
        out[0] = t / (float)BN;
        out[1] = c / (float)BN;
    }
}

extern "C" void kernel_launch(void* const* d_in, const int* in_sizes, int n_in,
                              void* d_out, int out_size, void* d_ws, size_t ws_size,
                              hipStream_t stream) {
    const float* feats    = (const float*)d_in[0];
    const int*   labels   = (const int*)d_in[1];
    const float* margin_p = (const float*)d_in[2];
    const float* sp_p     = (const float*)d_in[3];
    const float* sn_p     = (const float*)d_in[4];
    float* out = (float*)d_out;

    char* ws = (char*)d_ws;
    unsigned short* fb = (unsigned short*)ws;                         // 2 MB bf16 feats
    float* minp_part = (float*)(ws + (size_t)BN * DF * sizeof(unsigned short));
    float* maxn_part = minp_part + NSPLIT * BN;
    float* pos_sum   = maxn_part + NSPLIT * BN;
    float* neg_sum   = pos_sum + BN;

    hipMemsetAsync(pos_sum, 0, 2 * BN * sizeof(float), stream);

    convert_kernel<<<(BN * DF) / (256 * 8), 256, 0, stream>>>(feats, fb);
    phase1_kernel<<<(BN / ROWS_PER_BLK) * NSPLIT, 256, 0, stream>>>(fb, labels, minp_part, maxn_part);
    phase2_kernel<<<(BN / ROWS_PER_BLK) * NSPLIT, 256, 0, stream>>>(fb, labels, minp_part, maxn_part,
                                                                    pos_sum, neg_sum, margin_p, sp_p, sn_p);
    finalize_kernel<<<1, 256, 0, stream>>>(pos_sum, neg_sum, sp_p, sn_p, out);
}

// Round 3
// 173.767 us; speedup vs baseline: 1.6574x; 1.6574x over previous
//
#include <hip/hip_runtime.h>
#include <math.h>

#define BN 8192       // batch size (rows of sim)
#define DF 128        // feature dim
#define NSPLIT 16     // column splits per row-block
#define ROWS_PER_BLK 64
#define CB 64         // cols per LDS chunk
#define NCHUNK ((BN / NSPLIT) / CB)
#define EPSV 1e-5f
#define THRESH 0.5f

typedef short bf16x8 __attribute__((ext_vector_type(8)));
typedef float f32x4 __attribute__((ext_vector_type(4)));
typedef unsigned short ushortx8 __attribute__((ext_vector_type(8)));

static __device__ __forceinline__ unsigned short f2bf(float f) {
    unsigned u = __float_as_uint(f);
    u += 0x7FFFu + ((u >> 16) & 1u);   // round-to-nearest-even
    return (unsigned short)(u >> 16);
}

// Stage one 16KB chunk (64 cols x 256B) of fb into LDS with pre-swizzled
// global source (rule #21: linear LDS dest + inv-swz source + swz read).
// swizzle: off ^= ((off>>8)&7)<<4   (involution on 16B units within 256B rows)
static __device__ __forceinline__ void stage_chunk(const char* gbase, char* lds_buf,
                                                   int wave, int lane) {
    #pragma unroll
    for (int i = 0; i < 4; ++i) {
        int off = (wave * 4 + i) * 1024 + lane * 16;
        int src = off ^ (((off >> 8) & 7) << 4);
        __builtin_amdgcn_global_load_lds(
            (const __attribute__((address_space(1))) void*)(gbase + src),
            (__attribute__((address_space(3))) void*)(lds_buf + (wave * 4 + i) * 1024),
            16, 0, 0);
    }
}

// ---------------- kernel 0: f32 -> bf16 convert ----------------
__global__ __launch_bounds__(256) void convert_kernel(const float* __restrict__ in,
                                                      unsigned short* __restrict__ out) {
    int gid = blockIdx.x * 256 + threadIdx.x;       // 8 elems per thread
    const float4* inp = reinterpret_cast<const float4*>(in) + (size_t)gid * 2;
    float4 v0 = inp[0], v1 = inp[1];
    ushortx8 o;
    o[0] = f2bf(v0.x); o[1] = f2bf(v0.y); o[2] = f2bf(v0.z); o[3] = f2bf(v0.w);
    o[4] = f2bf(v1.x); o[5] = f2bf(v1.y); o[6] = f2bf(v1.z); o[7] = f2bf(v1.w);
    *reinterpret_cast<ushortx8*>(out + (size_t)gid * 8) = o;
}

// ---------------- kernel 1: per-row min_pos / max_neg ----------------
__global__ __launch_bounds__(256, 8) void phase1_kernel(const unsigned short* __restrict__ fb,
                                                        const int* __restrict__ labels,
                                                        float* __restrict__ minp_out,
                                                        float* __restrict__ maxn_out) {
    __shared__ char lds_buf[CB * 256];
    const int tid  = threadIdx.x;
    const int wave = tid >> 6, lane = tid & 63;
    const int rowblk = blockIdx.x >> 4;            // / NSPLIT
    const int split  = blockIdx.x & (NSPLIT - 1);
    const int m0w = rowblk * ROWS_PER_BLK + wave * 16;
    const int l4 = lane & 15, g = lane >> 4;

    // A fragments for this wave's 16 rows, all of K=128 (hoisted; direct global)
    bf16x8 afrag[4];
    const int arow = m0w + l4;
    #pragma unroll
    for (int kk = 0; kk < 4; ++kk)
        afrag[kk] = *reinterpret_cast<const bf16x8*>(fb + arow * DF + kk * 32 + g * 8);

    int rrow[4], labr[4];
    #pragma unroll
    for (int r = 0; r < 4; ++r) { rrow[r] = m0w + g * 4 + r; labr[r] = labels[rrow[r]]; }

    float minp[4], maxn[4];
    #pragma unroll
    for (int r = 0; r < 4; ++r) { minp[r] = INFINITY; maxn[r] = -INFINITY; }

    const int n_begin = split * (BN / NSPLIT);
    const char* fb_bytes = (const char*)fb;

    for (int chunk = 0; chunk < NCHUNK; ++chunk) {
        const int cbase = n_begin + chunk * CB;
        stage_chunk(fb_bytes + (size_t)cbase * 256, lds_buf, wave, lane);
        __syncthreads();   // drains vmcnt (compiler emits full waitcnt before barrier)

        #pragma unroll
        for (int t = 0; t < 4; ++t) {
            const int c   = t * 16 + l4;
            const int col = cbase + c;
            const int labc = labels[col];
            const int swx  = (c & 7) << 4;
            f32x4 acc = {0.f, 0.f, 0.f, 0.f};
            #pragma unroll
            for (int kk = 0; kk < 4; ++kk) {
                const int y = kk * 64 + g * 16;
                bf16x8 bfrag = *reinterpret_cast<const bf16x8*>(&lds_buf[c * 256 + (y ^ swx)]);
                acc = __builtin_amdgcn_mfma_f32_16x16x32_bf16(afrag[kk], bfrag, acc, 0, 0, 0);
            }
            #pragma unroll
            for (int r = 0; r < 4; ++r) {
                float s = acc[r];
                bool same = (labc == labr[r]);
                bool posc = same && (col != rrow[r]) && (s < 1.0f - EPSV);
                minp[r] = fminf(minp[r], posc ? s : INFINITY);
                maxn[r] = fmaxf(maxn[r], same ? -INFINITY : s);
            }
        }
        __syncthreads();   // protect LDS before next stage overwrites
    }

    #pragma unroll
    for (int r = 0; r < 4; ++r) {
        #pragma unroll
        for (int m = 1; m < 16; m <<= 1) {
            minp[r] = fminf(minp[r], __shfl_xor(minp[r], m, 64));
            maxn[r] = fmaxf(maxn[r], __shfl_xor(maxn[r], m, 64));
        }
        if (l4 == 0) {
            minp_out[split * BN + rrow[r]] = minp[r];
            maxn_out[split * BN + rrow[r]] = maxn[r];
        }
    }
}

// ---------------- kernel 2: masked exp sums ----------------
__global__ __launch_bounds__(256, 8) void phase2_kernel(const unsigned short* __restrict__ fb,
                                                        const int* __restrict__ labels,
                                                        const float* __restrict__ minp_part,
                                                        const float* __restrict__ maxn_part,
                                                        float* __restrict__ pos_sum,
                                                        float* __restrict__ neg_sum,
                                                        const float* __restrict__ margin_p,
                                                        const float* __restrict__ sp_p,
                                                        const float* __restrict__ sn_p) {
    __shared__ char lds_buf[CB * 256];
    const int tid  = threadIdx.x;
    const int wave = tid >> 6, lane = tid & 63;
    const int rowblk = blockIdx.x >> 4;
    const int split  = blockIdx.x & (NSPLIT - 1);
    const int m0w = rowblk * ROWS_PER_BLK + wave * 16;
    const int l4 = lane & 15, g = lane >> 4;

    const float margin = *margin_p;
    const float sp = *sp_p, sn = *sn_p;
    const float L2E = 1.4426950408889634f;
    const float a_pos = -sp * L2E, b_pos =  sp * THRESH * L2E;
    const float a_neg =  sn * L2E, b_neg = -sn * THRESH * L2E;

    bf16x8 afrag[4];
    const int arow = m0w + l4;
    #pragma unroll
    for (int kk = 0; kk < 4; ++kk)
        afrag[kk] = *reinterpret_cast<const bf16x8*>(fb + arow * DF + kk * 32 + g * 8);

    int rrow[4], labr[4];
    float thrn[4], tpos[4];
    #pragma unroll
    for (int r = 0; r < 4; ++r) {
        rrow[r] = m0w + g * 4 + r;
        labr[r] = labels[rrow[r]];
        float mp = INFINITY, mn = -INFINITY;
        #pragma unroll
        for (int s = 0; s < NSPLIT; ++s) {
            mp = fminf(mp, minp_part[s * BN + rrow[r]]);
            mn = fmaxf(mn, maxn_part[s * BN + rrow[r]]);
        }
        thrn[r] = mp - margin;                         // neg pair needs sim > thrn
        tpos[r] = fminf(mn + margin, 1.0f - EPSV);     // pos pair needs sim < tpos
    }

    float psum[4] = {0.f, 0.f, 0.f, 0.f};
    float nsum[4] = {0.f, 0.f, 0.f, 0.f};

    const int n_begin = split * (BN / NSPLIT);
    const char* fb_bytes = (const char*)fb;

    for (int chunk = 0; chunk < NCHUNK; ++chunk) {
        const int cbase = n_begin + chunk * CB;
        stage_chunk(fb_bytes + (size_t)cbase * 256, lds_buf, wave, lane);
        __syncthreads();

        #pragma unroll
        for (int t = 0; t < 4; ++t) {
            const int c   = t * 16 + l4;
            const int col = cbase + c;
            const int labc = labels[col];
            const int swx  = (c & 7) << 4;
            f32x4 acc = {0.f, 0.f, 0.f, 0.f};
            #pragma unroll
            for (int kk = 0; kk < 4; ++kk) {
                const int y = kk * 64 + g * 16;
                bf16x8 bfrag = *reinterpret_cast<const bf16x8*>(&lds_buf[c * 256 + (y ^ swx)]);
                acc = __builtin_amdgcn_mfma_f32_16x16x32_bf16(afrag[kk], bfrag, acc, 0, 0, 0);
            }
            #pragma unroll
            for (int r = 0; r < 4; ++r) {
                float s = acc[r];
                bool same = (labc == labr[r]);
                bool posc = same && (col != rrow[r]) && (s < tpos[r]);
                bool negc = (!same) && (s > thrn[r]);
                float aa = same ? a_pos : a_neg;
                float bb = same ? b_pos : b_neg;
                float e  = __builtin_amdgcn_exp2f(fmaf(aa, s, bb));
                psum[r] += posc ? e : 0.f;
                nsum[r] += negc ? e : 0.f;
            }
        }
        __syncthreads();
    }

    #pragma unroll
    for (int r = 0; r < 4; ++r) {
        #pragma unroll
        for (int m = 1; m < 16; m <<= 1) {
            psum[r] += __shfl_xor(psum[r], m, 64);
            nsum[r] += __shfl_xor(nsum[r], m, 64);
        }
        if (l4 == 0) {
            atomicAdd(&pos_sum[rrow[r]], psum[r]);
            atomicAdd(&neg_sum[rrow[r]], nsum[r]);
        }
    }
}

// ---------------- kernel 3: finalize ----------------
__global__ __launch_bounds__(256) void finalize_kernel(const float* __restrict__ pos_sum,
                                                       const float* __restrict__ neg_sum,
                                                       const float* __restrict__ sp_p,
                                                       const float* __restrict__ sn_p,
                                                       float* __restrict__ out) {
    const int tid  = threadIdx.x;
    const int wave = tid >> 6, lane = tid & 63;
    const float sp = *sp_p, sn = *sn_p;
    float lsum = 0.f, ncnt = 0.f;
    for (int r = tid; r < BN; r += 256) {
        float ps = pos_sum[r], ns = neg_sum[r];
        bool hasp = ps > 0.f, hasn = ns > 0.f;
        if (hasp && hasn) lsum += log1pf(ps) / sp + log1pf(ns) / sn;
        if (!hasn) ncnt += 1.f;
    }
    #pragma unroll
    for (int m = 1; m < 64; m <<= 1) {
        lsum += __shfl_xor(lsum, m, 64);
        ncnt += __shfl_xor(ncnt, m, 64);
    }
    __shared__ float sdata[8];
    if (lane == 0) { sdata[wave] = lsum; sdata[4 + wave] = ncnt; }
    __syncthreads();
    if (tid == 0) {
        float t = 0.f, c = 0.f;
        for (int i = 0; i < 4; ++i) { t += sdata[i]; c += sdata[4 + i]; }
        out[0] = t / (float)BN;
        out[1] = c / (float)BN;
    }
}

extern "C" void kernel_launch(void* const* d_in, const int* in_sizes, int n_in,
                              void* d_out, int out_size, void* d_ws, size_t ws_size,
                              hipStream_t stream) {
    const float* feats    = (const float*)d_in[0];
    const int*   labels   = (const int*)d_in[1];
    const float* margin_p = (const float*)d_in[2];
    const float* sp_p     = (const float*)d_in[3];
    const float* sn_p     = (const float*)d_in[4];
    float* out = (float*)d_out;

    char* ws = (char*)d_ws;
    unsigned short* fb = (unsigned short*)ws;                         // 2 MB bf16 feats
    float* minp_part = (float*)(ws + (size_t)BN * DF * sizeof(unsigned short));
    float* maxn_part = minp_part + NSPLIT * BN;
    float* pos_sum   = maxn_part + NSPLIT * BN;
    float* neg_sum   = pos_sum + BN;

    hipMemsetAsync(pos_sum, 0, 2 * BN * sizeof(float), stream);

    convert_kernel<<<(BN * DF) / (256 * 8), 256, 0, stream>>>(feats, fb);
    phase1_kernel<<<(BN / ROWS_PER_BLK) * NSPLIT, 256, 0, stream>>>(fb, labels, minp_part, maxn_part);
    phase2_kernel<<<(BN / ROWS_PER_BLK) * NSPLIT, 256, 0, stream>>>(fb, labels, minp_part, maxn_part,
                                                                    pos_sum, neg_sum, margin_p, sp_p, sn_p);
    finalize_kernel<<<1, 256, 0, stream>>>(pos_sum, neg_sum, sp_p, sn_p, out);
}